// Round 12
// baseline (170.229 us; speedup 1.0000x reference)
//
#include <hip/hip_runtime.h>
#include <hip/hip_bf16.h>

// Problem constants (from reference)
#define NW   8192
#define NS   8192
#define FD   1024
#define EMB  128
#define QN   1024
#define NC   80

typedef unsigned short ushort_t;
typedef unsigned int   uint_t;
typedef __attribute__((ext_vector_type(8))) short short8;
typedef __attribute__((ext_vector_type(4))) float f32x4;

// ---------- workspace layout (element offsets, 4B units) ----------
#define OFF_Q      0u           // float [NW*EMB]
#define OFF_K      1048576u     // float [NS*EMB]
#define OFF_WTQ    2097152u     // ushort[1024*128]
#define OFF_WTK    2129920u     // ushort[1024*128]
#define OFF_HIST   2752512u     // int   [128]
#define OFF_RANK   2752640u     // int   [NW]
#define OFF_CNT    2760832u     // int   [1] completion counter
#define OFF_BHS    2785408u     // int   [32*NC]
#define OFF_BHW    2787968u     // int   [32*NC]
#define OFF_ACC    2790528u     // float [2] : {sum_ce, valid_count}
#define OFF_QT     2790532u     // ushort[1024*128] (Qt: queue^T bf16)
#define OFF_TABLE  3000000u     // int   [NC*8192] — own region (no Wt alias; ranktab fused in enc)

__device__ __forceinline__ ushort_t f2bf(float f) {   // fp32 -> bf16 RNE
    uint_t u = __float_as_uint(f);
    u = (u + 0x7fffu + ((u >> 16) & 1u)) >> 16;
    return (ushort_t)u;
}
__device__ __forceinline__ uint_t pack2(float a, float b) {
    return (uint_t)f2bf(a) | ((uint_t)f2bf(b) << 16);
}

// async global->LDS, 16B per lane; LDS dest = WAVE-UNIFORM base + lane*16 (no per-lane scatter)
#define GLOAD_LDS16(gp, lp)                                                     \
    __builtin_amdgcn_global_load_lds(                                           \
        (const __attribute__((address_space(1))) void*)(gp),                    \
        (__attribute__((address_space(3))) void*)(lp), 16, 0, 0)

// ============ K1: fused convert/transpose + per-block label histograms + init ============
// z<2: W[1024][128] -> Wt tiled [kb(32)][kg(4)][n(128)][8]  (kb=k>>5, kg=(k>>3)&3)
// z=2: queue[128][1024] -> Qt[n][k] plain
__global__ __launch_bounds__(256) void cvtbh_k(const float* __restrict__ Wq,
                                               const float* __restrict__ Wk,
                                               const float* __restrict__ queue,
                                               const int* __restrict__ s_lab,
                                               const int* __restrict__ w_lab,
                                               ushort_t* __restrict__ Wtq,
                                               ushort_t* __restrict__ Wtk,
                                               ushort_t* __restrict__ Qt,
                                               int* __restrict__ bhs,
                                               int* __restrict__ bhw,
                                               float* __restrict__ accum,
                                               int* __restrict__ counter) {
    int bx = blockIdx.x;
    int t = threadIdx.x;
    if (bx >= 384) {   // ---- bh part ----
        __shared__ int h[NC];
        int b2 = bx - 384, z = b2 >> 5, cb = b2 & 31;
        const int* lab = z ? w_lab : s_lab;
        int* bh = z ? bhw : bhs;
        if (t < NC) h[t] = 0;
        __syncthreads();
        atomicAdd(&h[lab[cb * 256 + t]], 1);
        __syncthreads();
        if (t < NC) bh[cb * NC + t] = h[t];
        return;
    }
    // ---- cvt part ----
    __shared__ float tile[32][33];
    int z = bx >> 7, flat = bx & 127;
    if (z == 0 && flat == 0) {
        if (t < 2) accum[t] = 0.0f;
        if (t == 2) *counter = 0;
    }
    const float* in; ushort_t* out; int r0, c0, C;
    if (z < 2) { in = z ? Wk : Wq; out = z ? Wtk : Wtq; C = 128;
                 r0 = (flat >> 2) * 32; c0 = (flat & 3) * 32; }
    else       { in = queue; out = Qt; C = 1024;
                 r0 = (flat & 3) * 32; c0 = (flat >> 2) * 32; }
    int i = t >> 3, j0 = (t & 7) * 4;
    float4 v = *(const float4*)(in + (size_t)(r0 + i) * C + c0 + j0);
    tile[i][j0] = v.x; tile[i][j0 + 1] = v.y; tile[i][j0 + 2] = v.z; tile[i][j0 + 3] = v.w;
    __syncthreads();
    uint2 pk;
    pk.x = pack2(tile[j0][i], tile[j0 + 1][i]);
    pk.y = pack2(tile[j0 + 2][i], tile[j0 + 3][i]);
    size_t oaddr;
    if (z < 2) {
        int k0 = r0 + j0, n = c0 + i;   // 4 consecutive k at (k0..k0+3), n fixed
        oaddr = (size_t)(k0 >> 5) * 4096 + (size_t)((k0 >> 3) & 3) * 1024
              + (size_t)n * 8 + (k0 & 7);
    } else {
        oaddr = (size_t)(c0 + i) * 128 + (r0 + j0);   // plain [n][k]
    }
    *(uint2*)(out + oaddr) = pk;
}

// ============ K2: encoder GEMM (BK=32, 8 blocks/CU) + fused ranktab ============
// blocks [0,1024): GEMM — bx>>9 = encoder, bx&511 = 16-row tile; 4 waves N-split (32 cols each).
//   LDS/buf = 10KB: A 2KB (16 rows x 8 chunks of 4 fp32, slot = r*8 + (c ^ (r&7)),
//     XOR applied on the GLOBAL gather so DMA dest stays uniform+lane*16; reader 2-way = free),
//   B 8KB ([kg(4)][n(128)] 16B slots from Wt tiled [kb][kg][n][8]; DMA linear; reader bank
//     = (n*4)&31 -> 2-way = free). 20KB/block -> 8 blocks/CU = 32 waves/CU (max TLP
//     to absorb the per-barrier vmcnt drains).
// blocks [1024,1088): ranktab — rank/table/hist from the cvtbh block-histograms.
__global__ __launch_bounds__(256) void enc_mfma_k(const float* __restrict__ A0,
                                                  const float* __restrict__ A1,
                                                  const ushort_t* __restrict__ Wt0,
                                                  const ushort_t* __restrict__ Wt1,
                                                  const float* __restrict__ b0_,
                                                  const float* __restrict__ b1_,
                                                  float* __restrict__ out0,
                                                  float* __restrict__ out1,
                                                  const int* __restrict__ s_lab,
                                                  const int* __restrict__ w_lab,
                                                  const int* __restrict__ bhs,
                                                  const int* __restrict__ bhw,
                                                  int* __restrict__ table,
                                                  int* __restrict__ rank,
                                                  int* __restrict__ hist) {
    __shared__ __align__(16) char smem[20480];   // 2 x (2KB A + 8KB B); ranktab reuses 1KB

    int bx = blockIdx.x;
    int t = threadIdx.x;

    if (bx >= 1024) {   // ---- fused ranktab part ----
        int* ll = (int*)smem;
        int b2 = bx - 1024, z = b2 >> 5, cb = b2 & 31;
        const int* lab = z ? w_lab : s_lab;
        const int* bh = z ? bhw : bhs;
        int j = cb * 256 + t;
        int c = lab[j];
        ll[t] = c;
        __syncthreads();
        int r = 0;
        for (int b = 0; b < cb; b++) r += bh[b * NC + c];
        for (int jj = 0; jj < t; jj++) r += (ll[jj] == c) ? 1 : 0;
        if (z) rank[j] = r;
        else   table[c * 8192 + r] = j;
        if (b2 == 0 && t < 128) {
            int h = 0;
            if (t < NC)
                for (int b = 0; b < 32; b++) h += bhs[b * NC + t];
            hist[t] = h;
        }
        return;
    }

    // ---- GEMM part ----
    int which = bx >> 9;
    int mtile = bx & 511;
    const float*    A    = which ? A1 : A0;
    const ushort_t* Wt   = which ? Wt1 : Wt0;
    const float*    bias = which ? b1_ : b0_;
    float*          out  = which ? out1 : out0;
    int row0 = mtile * 16;

    int wv = t >> 6, ln = t & 63;
    int lane15 = ln & 15, kg = ln >> 4;

    // A staging (waves 0,1): lane -> row r = wv*8 + (ln>>3), XOR'd chunk c = (ln&7)^(ln>>3)
    const float* gA = A + (size_t)(row0 + wv * 8 + (ln >> 3)) * FD + ((ln & 7) ^ (ln >> 3)) * 4;
    // B staging (all waves, 2 instrs): slots (wv*2+i)*64 + ln, linear in tiled Wt
    const ushort_t* gB = Wt + (size_t)wv * 1024 + ln * 8;

    f32x4 acc0 = (f32x4){0.f, 0.f, 0.f, 0.f};
    f32x4 acc1 = (f32x4){0.f, 0.f, 0.f, 0.f};

#define STAGE(BUF, KB)                                                           \
    { char* lb = smem + (BUF) * 10240;                                           \
      if (wv < 2) GLOAD_LDS16(gA + (size_t)(KB) * 32, lb + wv * 1024);           \
      const ushort_t* gb = gB + (size_t)(KB) * 4096;                             \
      char* bb = lb + 2048 + wv * 2048;                                          \
      GLOAD_LDS16(gb,       bb);                                                 \
      GLOAD_LDS16(gb + 512, bb + 1024); }

    STAGE(0, 0)
    __syncthreads();

#pragma unroll 1
    for (int kb = 0; kb < 32; kb++) {
        int cur = kb & 1;
        if (kb < 31) STAGE(cur ^ 1, kb + 1)
        char* lb = smem + cur * 10240;
        // A frag: row lane15, chunks 2kg, 2kg+1 (XOR-swizzled slots)
        float4 alo = *(const float4*)(lb + (lane15 * 8 + ((2 * kg)     ^ (lane15 & 7))) * 16);
        float4 ahi = *(const float4*)(lb + (lane15 * 8 + ((2 * kg + 1) ^ (lane15 & 7))) * 16);
        uint4 pk;
        pk.x = pack2(alo.x, alo.y); pk.y = pack2(alo.z, alo.w);
        pk.z = pack2(ahi.x, ahi.y); pk.w = pack2(ahi.z, ahi.w);
        short8 af = __builtin_bit_cast(short8, pk);
        // B frags: slot = kg*128 + n, n = wv*32 + {0,16} + lane15
        uint4 bb0 = *(const uint4*)(lb + 2048 + ((size_t)kg * 128 + wv * 32 + lane15) * 16);
        uint4 bb1 = *(const uint4*)(lb + 2048 + ((size_t)kg * 128 + wv * 32 + 16 + lane15) * 16);
        acc0 = __builtin_amdgcn_mfma_f32_16x16x32_bf16(af, __builtin_bit_cast(short8, bb0), acc0, 0, 0, 0);
        acc1 = __builtin_amdgcn_mfma_f32_16x16x32_bf16(af, __builtin_bit_cast(short8, bb1), acc1, 0, 0, 0);
        __syncthreads();
    }
#undef STAGE

    // epilogue: C[row][col], row = row0 + kg*4+j, col = wv*32 + {0,16} + lane15
    {
        int col0 = wv * 32 + lane15, col1 = wv * 32 + 16 + lane15;
        float bv0 = bias[col0], bv1 = bias[col1];
        int rbase = row0 + kg * 4;
#pragma unroll
        for (int j = 0; j < 4; j++) {
            out[(size_t)(rbase + j) * EMB + col0] = acc0[j] + bv0;
            out[(size_t)(rbase + j) * EMB + col1] = acc1[j] + bv1;
        }
    }
}

// ============ K3: idx + lpos + l_neg (MFMA, register logits) + deferred softmax CE ========
// grid 512 x 256: 16 q-rows/block; 4 waves = 4 col-quarters (32 cols) of each 128-chunk.
__global__ __launch_bounds__(256, 2) void ce_mfma_k(const float* __restrict__ q,
                                                    const float* __restrict__ k,
                                                    const ushort_t* __restrict__ Qt,
                                                    const int* __restrict__ rank,
                                                    const int* __restrict__ table,
                                                    const int* __restrict__ w,
                                                    const int* __restrict__ hist,
                                                    float* __restrict__ accum,
                                                    int* __restrict__ counter,
                                                    float* __restrict__ outp) {
    __shared__ int   idx_lds[16];
    __shared__ float lpos_lds[16];
    __shared__ float mg[4][16][2];
    int t = threadIdx.x;
    int r0 = blockIdx.x * 16;

    // inline idx: idx[i] = table[w[i]][rank[i] % cnt]
    if (t < 16) {
        int i = r0 + t;
        int c = w[i];
        int cc = hist[c];
        idx_lds[t] = (cc > 0) ? table[c * 8192 + (rank[i] % cc)] : 0;
    }
    __syncthreads();

    // fused l_pos (fp32 exact): row r0+(t>>4), 16 threads x 8 floats
    {
        int rr = t >> 4;
        int o = (t & 15) * 8;
        const float4* qa = (const float4*)(q + (size_t)(r0 + rr) * EMB + o);
        const float4* ka = (const float4*)(k + (size_t)idx_lds[rr] * EMB + o);
        float4 a0 = qa[0], b0 = ka[0], a1 = qa[1], b1 = ka[1];
        float s = a0.x * b0.x + a0.y * b0.y + a0.z * b0.z + a0.w * b0.w
                + a1.x * b1.x + a1.y * b1.y + a1.z * b1.z + a1.w * b1.w;
        s += __shfl_xor(s, 1); s += __shfl_xor(s, 2);
        s += __shfl_xor(s, 4); s += __shfl_xor(s, 8);
        if ((t & 15) == 0) lpos_lds[rr] = s;
    }

    int wv = t >> 6, ln = t & 63;
    int lane15 = ln & 15, kg = ln >> 4;

    // A-frags direct from q global (all waves same 16 rows)
    short8 afr[4];
#pragma unroll
    for (int ks = 0; ks < 4; ks++) {
        const float4* p = (const float4*)(q + (size_t)(r0 + lane15) * EMB + ks * 32 + kg * 8);
        float4 a = p[0], b = p[1];
        uint4 pk;
        pk.x = pack2(a.x, a.y); pk.y = pack2(a.z, a.w);
        pk.z = pack2(b.x, b.y); pk.w = pack2(b.z, b.w);
        afr[ks] = __builtin_bit_cast(short8, pk);
    }

    // all logits in registers: accA[nc] = cols wv*32+lane15, accB[nc] = +16
    f32x4 accA[8], accB[8];
#pragma unroll
    for (int nc = 0; nc < 8; nc++) {
        accA[nc] = (f32x4){0.f, 0.f, 0.f, 0.f};
        accB[nc] = (f32x4){0.f, 0.f, 0.f, 0.f};
    }
#pragma unroll
    for (int nc = 0; nc < 8; nc++) {
        size_t nrow0 = (size_t)(nc * 128 + wv * 32 + lane15) * 128 + kg * 8;
#pragma unroll
        for (int ks = 0; ks < 4; ks++) {
            short8 bf0 = __builtin_bit_cast(short8, *(const uint4*)(Qt + nrow0 + ks * 32));
            short8 bf1 = __builtin_bit_cast(short8, *(const uint4*)(Qt + nrow0 + 16 * 128 + ks * 32));
            accA[nc] = __builtin_amdgcn_mfma_f32_16x16x32_bf16(afr[ks], bf0, accA[nc], 0, 0, 0);
            accB[nc] = __builtin_amdgcn_mfma_f32_16x16x32_bf16(afr[ks], bf1, accB[nc], 0, 0, 0);
        }
    }

    // deferred softmax: one max/exp/sum pass over the 64 register logits
#pragma unroll
    for (int j = 0; j < 4; j++) {
        float mx = -1e30f;
#pragma unroll
        for (int nc = 0; nc < 8; nc++) mx = fmaxf(mx, fmaxf(accA[nc][j], accB[nc][j]));
        mx = fmaxf(mx, __shfl_xor(mx, 1));
        mx = fmaxf(mx, __shfl_xor(mx, 2));
        mx = fmaxf(mx, __shfl_xor(mx, 4));
        mx = fmaxf(mx, __shfl_xor(mx, 8));
        float s = 0.f;
#pragma unroll
        for (int nc = 0; nc < 8; nc++)
            s += __expf(accA[nc][j] - mx) + __expf(accB[nc][j] - mx);
        s += __shfl_xor(s, 1);
        s += __shfl_xor(s, 2);
        s += __shfl_xor(s, 4);
        s += __shfl_xor(s, 8);
        if (lane15 == 0) {
            mg[wv][kg * 4 + j][0] = mx;
            mg[wv][kg * 4 + j][1] = s;
        }
    }
    __syncthreads();
    if (wv == 0) {
        float cv = 0.f, cc = 0.f;
        if (t < 16) {
            int i = r0 + t;
            float m0 = mg[0][t][0], l0 = mg[0][t][1];
            float m1 = mg[1][t][0], l1 = mg[1][t][1];
            float m2 = mg[2][t][0], l2 = mg[2][t][1];
            float m3 = mg[3][t][0], l3 = mg[3][t][1];
            float lp = lpos_lds[t];
            float m = fmaxf(fmaxf(fmaxf(m0, m1), fmaxf(m2, m3)), lp);
            float l = l0 * __expf(m0 - m) + l1 * __expf(m1 - m)
                    + l2 * __expf(m2 - m) + l3 * __expf(m3 - m) + __expf(lp - m);
            float ce = -(lp - m - __logf(l));
            if (hist[w[i]] > 0) { cv = ce; cc = 1.f; }
        }
        cv += __shfl_xor(cv, 1);  cc += __shfl_xor(cc, 1);
        cv += __shfl_xor(cv, 2);  cc += __shfl_xor(cc, 2);
        cv += __shfl_xor(cv, 4);  cc += __shfl_xor(cc, 4);
        cv += __shfl_xor(cv, 8);  cc += __shfl_xor(cc, 8);
        if (t == 0) {
            atomicAdd(&accum[0], cv);
            atomicAdd(&accum[1], cc);
            __threadfence();
            int done = atomicAdd(counter, 1);
            if (done == 511) {   // last block finalizes
                float s = atomicAdd(&accum[0], 0.0f);
                float c = atomicAdd(&accum[1], 0.0f);
                outp[0] = s / fmaxf(c, 1.0f);
            }
        }
    }
}

extern "C" void kernel_launch(void* const* d_in, const int* in_sizes, int n_in,
                              void* d_out, int out_size, void* d_ws, size_t ws_size,
                              hipStream_t stream) {
    const float* feats_strong = (const float*)d_in[0];
    const float* feats_weak   = (const float*)d_in[1];
    const int*   s_lab        = (const int*)d_in[2];
    const int*   w_lab        = (const int*)d_in[3];
    const float* Wq           = (const float*)d_in[4];
    const float* bq           = (const float*)d_in[5];
    const float* Wk           = (const float*)d_in[6];
    const float* bk           = (const float*)d_in[7];
    const float* queue        = (const float*)d_in[8];

    float*    wsf = (float*)d_ws;
    int*      wsi = (int*)d_ws;

    float*    q_g   = wsf + OFF_Q;
    float*    k_g   = wsf + OFF_K;
    int*      table = wsi + OFF_TABLE;
    ushort_t* Wtq   = (ushort_t*)(wsi + OFF_WTQ);
    ushort_t* Wtk   = (ushort_t*)(wsi + OFF_WTK);
    int*      hist  = wsi + OFF_HIST;
    int*      rank  = wsi + OFF_RANK;
    int*      cnt   = wsi + OFF_CNT;
    int*      bhs   = wsi + OFF_BHS;
    int*      bhw   = wsi + OFF_BHW;
    float*    accum = wsf + OFF_ACC;
    ushort_t* Qt    = (ushort_t*)(wsi + OFF_QT);

    // K1: bf16 convert/transpose + label block-histograms + zero accum/counter
    cvtbh_k<<<448, 256, 0, stream>>>(Wq, Wk, queue, s_lab, w_lab,
                                     Wtq, Wtk, Qt, bhs, bhw, accum, cnt);
    // K2: both encoder GEMMs + fused ranktab (independent blocks)
    enc_mfma_k<<<1088, 256, 0, stream>>>(feats_weak, feats_strong, Wtq, Wtk, bq, bk, q_g, k_g,
                                         s_lab, w_lab, bhs, bhw, table, rank, hist);
    // K3: idx + lpos + l_neg GEMM + CE + finalize
    ce_mfma_k<<<512, 256, 0, stream>>>(q_g, k_g, Qt, rank, table, w_lab, hist,
                                       accum, cnt, (float*)d_out);
}

// Round 13
// 154.494 us; speedup vs baseline: 1.1018x; 1.1018x over previous
//
#include <hip/hip_runtime.h>
#include <hip/hip_bf16.h>

// Problem constants (from reference)
#define NW   8192
#define NS   8192
#define FD   1024
#define EMB  128
#define QN   1024
#define NC   80

typedef unsigned short ushort_t;
typedef unsigned int   uint_t;
typedef __attribute__((ext_vector_type(8))) short short8;
typedef __attribute__((ext_vector_type(4))) float f32x4;

// ---------- workspace layout (element offsets, 4B units) ----------
#define OFF_Q      0u           // float [NW*EMB]
#define OFF_K      1048576u     // float [NS*EMB]
#define OFF_WTQ    2097152u     // ushort[1024*128]  tiled [kb(16)][kg(8)][n(128)][8]
#define OFF_WTK    2129920u     // ushort[1024*128]
#define OFF_HIST   2752512u     // int   [128]
#define OFF_RANK   2752640u     // int   [NW]
#define OFF_CNT    2760832u     // int   [1] completion counter
#define OFF_BHS    2785408u     // int   [32*NC]
#define OFF_BHW    2787968u     // int   [32*NC]
#define OFF_ACC    2790528u     // float [2] : {sum_ce, valid_count}
#define OFF_QT     2790532u     // ushort[1024*128]  swizzled slots: n*16 + (c ^ (n&15))
#define OFF_TABLE  3000000u     // int   [NC*8192]

__device__ __forceinline__ ushort_t f2bf(float f) {   // fp32 -> bf16 RNE
    uint_t u = __float_as_uint(f);
    u = (u + 0x7fffu + ((u >> 16) & 1u)) >> 16;
    return (ushort_t)u;
}
__device__ __forceinline__ uint_t pack2(float a, float b) {
    return (uint_t)f2bf(a) | ((uint_t)f2bf(b) << 16);
}

// async global->LDS, 16B per lane; LDS dest = WAVE-UNIFORM base + lane*16
#define GLOAD_LDS16(gp, lp)                                                     \
    __builtin_amdgcn_global_load_lds(                                           \
        (const __attribute__((address_space(1))) void*)(gp),                    \
        (__attribute__((address_space(3))) void*)(lp), 16, 0, 0)

// ============ K1: fused convert/transpose + per-block label histograms + init ============
// z<2: W[1024][128] -> Wt tiled [kb(16)][kg(8)][n(128)][8]  (k = kb*64 + kg*8 + j)
// z=2: queue[128][1024] -> Qt swizzled: 16B slot (n*16 + ((k>>3) ^ (n&15)))
__global__ __launch_bounds__(256) void cvtbh_k(const float* __restrict__ Wq,
                                               const float* __restrict__ Wk,
                                               const float* __restrict__ queue,
                                               const int* __restrict__ s_lab,
                                               const int* __restrict__ w_lab,
                                               ushort_t* __restrict__ Wtq,
                                               ushort_t* __restrict__ Wtk,
                                               ushort_t* __restrict__ Qt,
                                               int* __restrict__ bhs,
                                               int* __restrict__ bhw,
                                               float* __restrict__ accum,
                                               int* __restrict__ counter) {
    int bx = blockIdx.x;
    int t = threadIdx.x;
    if (bx >= 384) {   // ---- bh part ----
        __shared__ int h[NC];
        int b2 = bx - 384, z = b2 >> 5, cb = b2 & 31;
        const int* lab = z ? w_lab : s_lab;
        int* bh = z ? bhw : bhs;
        if (t < NC) h[t] = 0;
        __syncthreads();
        atomicAdd(&h[lab[cb * 256 + t]], 1);
        __syncthreads();
        if (t < NC) bh[cb * NC + t] = h[t];
        return;
    }
    // ---- cvt part ----
    __shared__ float tile[32][33];
    int z = bx >> 7, flat = bx & 127;
    if (z == 0 && flat == 0) {
        if (t < 2) accum[t] = 0.0f;
        if (t == 2) *counter = 0;
    }
    const float* in; ushort_t* out; int r0, c0, C;
    if (z < 2) { in = z ? Wk : Wq; out = z ? Wtk : Wtq; C = 128;
                 r0 = (flat >> 2) * 32; c0 = (flat & 3) * 32; }
    else       { in = queue; out = Qt; C = 1024;
                 r0 = (flat & 3) * 32; c0 = (flat >> 2) * 32; }
    int i = t >> 3, j0 = (t & 7) * 4;
    float4 v = *(const float4*)(in + (size_t)(r0 + i) * C + c0 + j0);
    tile[i][j0] = v.x; tile[i][j0 + 1] = v.y; tile[i][j0 + 2] = v.z; tile[i][j0 + 3] = v.w;
    __syncthreads();
    uint2 pk;
    pk.x = pack2(tile[j0][i], tile[j0 + 1][i]);
    pk.y = pack2(tile[j0 + 2][i], tile[j0 + 3][i]);
    size_t oaddr;
    int k0 = r0 + j0, n = c0 + i;
    if (z < 2) {
        oaddr = (size_t)(k0 >> 6) * 8192 + (size_t)((k0 >> 3) & 7) * 1024
              + (size_t)n * 8 + (k0 & 7);
    } else {
        int c = k0 >> 3;
        oaddr = ((size_t)n * 16 + (c ^ (n & 15))) * 8 + (k0 & 7);
    }
    *(uint2*)(out + oaddr) = pk;
}

// ============ K2: encoder GEMM (32x128 tile, BK=64, DMA dbuf) + fused ranktab ============
// blocks [0,512): GEMM — bx>>8 = encoder, bx&255 = 32-row tile; 4 waves 2x2 (wm,wn).
//   LDS/buf = 24KB: A 8KB (32 rows x 16 chunks of 4 fp32, slot = r*16 + (c ^ (r&15)),
//     XOR applied on the GLOBAL gather; reader phase bank group = (c^r)&7 distinct -> free),
//   B 16KB ([kg(8)][n(128)] slots from Wt tiled; DMA linear; reader 2-way -> free).
//   16 barriers; per wave per barrier: 8 MFMA + 12 ds_read_b128 + 6 DMA.
// blocks [512,576): ranktab — rank/table/hist from cvtbh block-histograms.
__global__ __launch_bounds__(256) void enc_mfma_k(const float* __restrict__ A0,
                                                  const float* __restrict__ A1,
                                                  const ushort_t* __restrict__ Wt0,
                                                  const ushort_t* __restrict__ Wt1,
                                                  const float* __restrict__ b0_,
                                                  const float* __restrict__ b1_,
                                                  float* __restrict__ out0,
                                                  float* __restrict__ out1,
                                                  const int* __restrict__ s_lab,
                                                  const int* __restrict__ w_lab,
                                                  const int* __restrict__ bhs,
                                                  const int* __restrict__ bhw,
                                                  int* __restrict__ table,
                                                  int* __restrict__ rank,
                                                  int* __restrict__ hist) {
    __shared__ __align__(16) char smem[49152];   // 2 x (8KB A + 16KB B)

    int bx = blockIdx.x;
    int t = threadIdx.x;

    if (bx >= 512) {   // ---- fused ranktab part ----
        int* ll = (int*)smem;
        int b2 = bx - 512, z = b2 >> 5, cb = b2 & 31;
        const int* lab = z ? w_lab : s_lab;
        const int* bh = z ? bhw : bhs;
        int j = cb * 256 + t;
        int c = lab[j];
        ll[t] = c;
        __syncthreads();
        int r = 0;
        for (int b = 0; b < cb; b++) r += bh[b * NC + c];
        for (int jj = 0; jj < t; jj++) r += (ll[jj] == c) ? 1 : 0;
        if (z) rank[j] = r;
        else   table[c * 8192 + r] = j;
        if (b2 == 0 && t < 128) {
            int h = 0;
            if (t < NC)
                for (int b = 0; b < 32; b++) h += bhs[b * NC + t];
            hist[t] = h;
        }
        return;
    }

    // ---- GEMM part ----
    int which = bx >> 8;
    int mtile = bx & 255;
    const float*    A    = which ? A1 : A0;
    const ushort_t* Wt   = which ? Wt1 : Wt0;
    const float*    bias = which ? b1_ : b0_;
    float*          out  = which ? out1 : out0;
    int row0 = mtile * 32;

    int wv = t >> 6, ln = t & 63;
    int wm = wv >> 1, wn = wv & 1;
    int lane15 = ln & 15, kg = ln >> 4;

    // A staging: wave wv, instr i in {0,1}: slot = wv*128 + i*64 + ln -> row r = slot>>4,
    // slot_c = ln&15, global chunk c_g = (ln&15) ^ (r&15)
    int ar0 = wv * 8 + (ln >> 4);
    int ar1 = ar0 + 4;
    const float* gA0 = A + (size_t)(row0 + ar0) * FD + (((ln & 15) ^ (ar0 & 15))) * 4;
    const float* gA1 = A + (size_t)(row0 + ar1) * FD + (((ln & 15) ^ (ar1 & 15))) * 4;
    // B staging: wave wv covers slots wv*256 + i*64 + ln (i 0..3), linear in tiled Wt
    const ushort_t* gB = Wt + (size_t)wv * 2048 + ln * 8;

    f32x4 acc[4];
#pragma unroll
    for (int nt = 0; nt < 4; nt++) acc[nt] = (f32x4){0.f, 0.f, 0.f, 0.f};

#define STAGE(BUF, KB)                                                           \
    { char* lb = smem + (BUF) * 24576;                                           \
      GLOAD_LDS16(gA0 + (size_t)(KB) * 64, lb + wv * 2048);                      \
      GLOAD_LDS16(gA1 + (size_t)(KB) * 64, lb + wv * 2048 + 1024);               \
      const ushort_t* gb = gB + (size_t)(KB) * 8192;                             \
      char* bb = lb + 8192 + wv * 4096;                                          \
      GLOAD_LDS16(gb,        bb);                                                \
      GLOAD_LDS16(gb + 512,  bb + 1024);                                         \
      GLOAD_LDS16(gb + 1024, bb + 2048);                                         \
      GLOAD_LDS16(gb + 1536, bb + 3072); }

    STAGE(0, 0)
    __syncthreads();

#pragma unroll 1
    for (int kb = 0; kb < 16; kb++) {
        int cur = kb & 1;
        if (kb < 15) STAGE(cur ^ 1, kb + 1)
        char* lb = smem + cur * 24576;
#pragma unroll
        for (int ks = 0; ks < 2; ks++) {
            int r_l = wm * 16 + lane15;
            int c0 = ks * 8 + kg * 2;
            float4 alo = *(const float4*)(lb + ((size_t)r_l * 16 + ((c0)     ^ (r_l & 15))) * 16);
            float4 ahi = *(const float4*)(lb + ((size_t)r_l * 16 + ((c0 + 1) ^ (r_l & 15))) * 16);
            uint4 pk;
            pk.x = pack2(alo.x, alo.y); pk.y = pack2(alo.z, alo.w);
            pk.z = pack2(ahi.x, ahi.y); pk.w = pack2(ahi.z, ahi.w);
            short8 af = __builtin_bit_cast(short8, pk);
            int kgg = ks * 4 + kg;
#pragma unroll
            for (int nt = 0; nt < 4; nt++) {
                uint4 bb = *(const uint4*)(lb + 8192 +
                            ((size_t)kgg * 128 + wn * 64 + nt * 16 + lane15) * 16);
                acc[nt] = __builtin_amdgcn_mfma_f32_16x16x32_bf16(
                    af, __builtin_bit_cast(short8, bb), acc[nt], 0, 0, 0);
            }
        }
        __syncthreads();
    }
#undef STAGE

    // epilogue: C[row][col], row = row0 + wm*16 + kg*4+j, col = wn*64 + nt*16 + lane15
#pragma unroll
    for (int nt = 0; nt < 4; nt++) {
        int col = wn * 64 + nt * 16 + lane15;
        float bv = bias[col];
        int rbase = row0 + wm * 16 + kg * 4;
#pragma unroll
        for (int j = 0; j < 4; j++)
            out[(size_t)(rbase + j) * EMB + col] = acc[nt][j] + bv;
    }
}

// ============ K3: idx + lpos + l_neg (MFMA, LDS-staged B, register logits) + CE ============
// grid 512 x 256: 16 q-rows/block; 16 col-chunks of 64 (Qt swizzled, DMA dbuf 2x16KB).
// Wave wv owns n_local = wv*16 + lane15 per chunk -> 16 chunks x 4 logits/lane = 64 regs.
__global__ __launch_bounds__(256, 2) void ce_mfma_k(const float* __restrict__ q,
                                                    const float* __restrict__ k,
                                                    const ushort_t* __restrict__ Qt,
                                                    const int* __restrict__ rank,
                                                    const int* __restrict__ table,
                                                    const int* __restrict__ w,
                                                    const int* __restrict__ hist,
                                                    float* __restrict__ accum,
                                                    int* __restrict__ counter,
                                                    float* __restrict__ outp) {
    __shared__ __align__(16) char bsm[32768];    // 2 x 16KB B chunks
    __shared__ int   idx_lds[16];
    __shared__ float lpos_lds[16];
    __shared__ float mg[4][16][2];
    int t = threadIdx.x;
    int r0 = blockIdx.x * 16;

    // inline idx: idx[i] = table[w[i]][rank[i] % cnt]
    if (t < 16) {
        int i = r0 + t;
        int c = w[i];
        int cc = hist[c];
        idx_lds[t] = (cc > 0) ? table[c * 8192 + (rank[i] % cc)] : 0;
    }
    __syncthreads();

    // fused l_pos (fp32 exact): row r0+(t>>4), 16 threads x 8 floats
    {
        int rr = t >> 4;
        int o = (t & 15) * 8;
        const float4* qa = (const float4*)(q + (size_t)(r0 + rr) * EMB + o);
        const float4* ka = (const float4*)(k + (size_t)idx_lds[rr] * EMB + o);
        float4 a0 = qa[0], b0 = ka[0], a1 = qa[1], b1 = ka[1];
        float s = a0.x * b0.x + a0.y * b0.y + a0.z * b0.z + a0.w * b0.w
                + a1.x * b1.x + a1.y * b1.y + a1.z * b1.z + a1.w * b1.w;
        s += __shfl_xor(s, 1); s += __shfl_xor(s, 2);
        s += __shfl_xor(s, 4); s += __shfl_xor(s, 8);
        if ((t & 15) == 0) lpos_lds[rr] = s;
    }

    int wv = t >> 6, ln = t & 63;
    int lane15 = ln & 15, kg = ln >> 4;

    // A-frags direct from q global (all waves same 16 rows)
    short8 afr[4];
#pragma unroll
    for (int ks = 0; ks < 4; ks++) {
        const float4* p = (const float4*)(q + (size_t)(r0 + lane15) * EMB + ks * 32 + kg * 8);
        float4 a = p[0], b = p[1];
        uint4 pk;
        pk.x = pack2(a.x, a.y); pk.y = pack2(a.z, a.w);
        pk.z = pack2(b.x, b.y); pk.w = pack2(b.z, b.w);
        afr[ks] = __builtin_bit_cast(short8, pk);
    }

    f32x4 acc[16];
#pragma unroll
    for (int nc = 0; nc < 16; nc++) acc[nc] = (f32x4){0.f, 0.f, 0.f, 0.f};

    // B staging: chunk nc = 64 cols x 128 k = 16KB; wave wv stages slots wv*256 + i*64 + ln
#define STAGE_CE(BUF, NC)                                                        \
    { char* lb = bsm + (BUF) * 16384;                                            \
      const ushort_t* src = Qt + (size_t)(NC) * 8192 + wv * 2048 + ln * 8;       \
      char* bb = lb + wv * 4096;                                                 \
      GLOAD_LDS16(src,        bb);                                               \
      GLOAD_LDS16(src + 512,  bb + 1024);                                        \
      GLOAD_LDS16(src + 1024, bb + 2048);                                        \
      GLOAD_LDS16(src + 1536, bb + 3072); }

    STAGE_CE(0, 0)
    __syncthreads();

#pragma unroll
    for (int nc = 0; nc < 16; nc++) {
        int cur = nc & 1;
        if (nc < 15) STAGE_CE(cur ^ 1, nc + 1)
        char* lb = bsm + cur * 16384;
        int n_l = wv * 16 + lane15;
#pragma unroll
        for (int ks = 0; ks < 4; ks++) {
            int c = ks * 4 + kg;
            uint4 bb = *(const uint4*)(lb + ((size_t)n_l * 16 + (c ^ lane15)) * 16);
            acc[nc] = __builtin_amdgcn_mfma_f32_16x16x32_bf16(
                afr[ks], __builtin_bit_cast(short8, bb), acc[nc], 0, 0, 0);
        }
        __syncthreads();
    }
#undef STAGE_CE

    // deferred softmax: one max/exp/sum pass over the 64 register logits
#pragma unroll
    for (int j = 0; j < 4; j++) {
        float mx = -1e30f;
#pragma unroll
        for (int nc = 0; nc < 16; nc++) mx = fmaxf(mx, acc[nc][j]);
        mx = fmaxf(mx, __shfl_xor(mx, 1));
        mx = fmaxf(mx, __shfl_xor(mx, 2));
        mx = fmaxf(mx, __shfl_xor(mx, 4));
        mx = fmaxf(mx, __shfl_xor(mx, 8));
        float s = 0.f;
#pragma unroll
        for (int nc = 0; nc < 16; nc++) s += __expf(acc[nc][j] - mx);
        s += __shfl_xor(s, 1);
        s += __shfl_xor(s, 2);
        s += __shfl_xor(s, 4);
        s += __shfl_xor(s, 8);
        if (lane15 == 0) {
            mg[wv][kg * 4 + j][0] = mx;
            mg[wv][kg * 4 + j][1] = s;
        }
    }
    __syncthreads();
    if (wv == 0) {
        float cv = 0.f, cc = 0.f;
        if (t < 16) {
            int i = r0 + t;
            float m0 = mg[0][t][0], l0 = mg[0][t][1];
            float m1 = mg[1][t][0], l1 = mg[1][t][1];
            float m2 = mg[2][t][0], l2 = mg[2][t][1];
            float m3 = mg[3][t][0], l3 = mg[3][t][1];
            float lp = lpos_lds[t];
            float m = fmaxf(fmaxf(fmaxf(m0, m1), fmaxf(m2, m3)), lp);
            float l = l0 * __expf(m0 - m) + l1 * __expf(m1 - m)
                    + l2 * __expf(m2 - m) + l3 * __expf(m3 - m) + __expf(lp - m);
            float ce = -(lp - m - __logf(l));
            if (hist[w[i]] > 0) { cv = ce; cc = 1.f; }
        }
        cv += __shfl_xor(cv, 1);  cc += __shfl_xor(cc, 1);
        cv += __shfl_xor(cv, 2);  cc += __shfl_xor(cc, 2);
        cv += __shfl_xor(cv, 4);  cc += __shfl_xor(cc, 4);
        cv += __shfl_xor(cv, 8);  cc += __shfl_xor(cc, 8);
        if (t == 0) {
            atomicAdd(&accum[0], cv);
            atomicAdd(&accum[1], cc);
            __threadfence();
            int done = atomicAdd(counter, 1);
            if (done == 511) {   // last block finalizes
                float s = atomicAdd(&accum[0], 0.0f);
                float c = atomicAdd(&accum[1], 0.0f);
                outp[0] = s / fmaxf(c, 1.0f);
            }
        }
    }
}

extern "C" void kernel_launch(void* const* d_in, const int* in_sizes, int n_in,
                              void* d_out, int out_size, void* d_ws, size_t ws_size,
                              hipStream_t stream) {
    const float* feats_strong = (const float*)d_in[0];
    const float* feats_weak   = (const float*)d_in[1];
    const int*   s_lab        = (const int*)d_in[2];
    const int*   w_lab        = (const int*)d_in[3];
    const float* Wq           = (const float*)d_in[4];
    const float* bq           = (const float*)d_in[5];
    const float* Wk           = (const float*)d_in[6];
    const float* bk           = (const float*)d_in[7];
    const float* queue        = (const float*)d_in[8];

    float*    wsf = (float*)d_ws;
    int*      wsi = (int*)d_ws;

    float*    q_g   = wsf + OFF_Q;
    float*    k_g   = wsf + OFF_K;
    int*      table = wsi + OFF_TABLE;
    ushort_t* Wtq   = (ushort_t*)(wsi + OFF_WTQ);
    ushort_t* Wtk   = (ushort_t*)(wsi + OFF_WTK);
    int*      hist  = wsi + OFF_HIST;
    int*      rank  = wsi + OFF_RANK;
    int*      cnt   = wsi + OFF_CNT;
    int*      bhs   = wsi + OFF_BHS;
    int*      bhw   = wsi + OFF_BHW;
    float*    accum = wsf + OFF_ACC;
    ushort_t* Qt    = (ushort_t*)(wsi + OFF_QT);

    // K1: bf16 convert/transpose (BK=64 W-tiling, swizzled Qt) + histograms + init
    cvtbh_k<<<448, 256, 0, stream>>>(Wq, Wk, queue, s_lab, w_lab,
                                     Wtq, Wtk, Qt, bhs, bhw, accum, cnt);
    // K2: both encoder GEMMs (32x128 tiles) + fused ranktab
    enc_mfma_k<<<576, 256, 0, stream>>>(feats_weak, feats_strong, Wtq, Wtk, bq, bk, q_g, k_g,
                                        s_lab, w_lab, bhs, bhw, table, rank, hist);
    // K3: idx + lpos + l_neg GEMM (LDS-staged) + CE + finalize
    ce_mfma_k<<<512, 256, 0, stream>>>(q_g, k_g, Qt, rank, table, w_lab, hist,
                                       accum, cnt, (float*)d_out);
}